// Round 10
// baseline (283.397 us; speedup 1.0000x reference)
//
#include <hip/hip_runtime.h>
#include <math.h>

typedef unsigned short ushortT;
typedef short short8 __attribute__((ext_vector_type(8)));
typedef float f32x4 __attribute__((ext_vector_type(4)));

#define D_STATE 16
#define D_INNER 1800
#define DT_RANK 57
#define SEQ_L 900
#define MROWS 1800            // 2*900
#define MP 1920               // padded rows
#define KP_DM 960             // K=900 pad
#define KP_DI 1856            // K=1800 pad
#define KP_DT 64              // K=57 pad
#define NCHUNK 45
#define CLEN 20

__device__ __forceinline__ ushortT f2bf(float f) {
    unsigned u = __float_as_uint(f);
    unsigned r = (u + 0x7FFFu + ((u >> 16) & 1u)) >> 16;
    return (ushortT)r;
}
__device__ __forceinline__ float bf2f(ushortT h) {
    return __uint_as_float((unsigned)h << 16);
}
__device__ __forceinline__ float silu_f(float x) { return x / (1.f + __expf(-x)); }
__device__ __forceinline__ float softplus_f(float x) {
    return fmaxf(x, 0.f) + __logf(1.f + __expf(-fabsf(x)));
}

__device__ __forceinline__ void gload_lds16(const ushortT* g, ushortT* l) {
    __builtin_amdgcn_global_load_lds((const __attribute__((address_space(1))) unsigned int*)g,
                                     (__attribute__((address_space(3))) unsigned int*)l,
                                     16, 0, 0);
}

// ---------------- all fp32->bf16 pad conversions in ONE kernel (8 cols/thread) ----------------
__global__ __launch_bounds__(256)
void cvt_all_k(const float* __restrict__ s0, ushortT* __restrict__ d0,   // inp 1800x900
               const float* __restrict__ s1, ushortT* __restrict__ d1,   // W_emb 900x900
               const float* __restrict__ s2, ushortT* __restrict__ d2,   // W_in 3600x900
               const float* __restrict__ s3, ushortT* __restrict__ d3,   // W_xp 89x1800
               const float* __restrict__ s4, ushortT* __restrict__ d4,   // W_dt 1800x57
               const float* __restrict__ s5, ushortT* __restrict__ d5)   // W_out 900x1800
{
    const float* src; ushortT* dst; int M, K, Mp, Kp;
    switch (blockIdx.y) {
      case 0: src=s0; dst=d0; M=1800; K=900;  Mp=1920; Kp=960;  break;
      case 1: src=s1; dst=d1; M=900;  K=900;  Mp=1024; Kp=960;  break;
      case 2: src=s2; dst=d2; M=3600; K=900;  Mp=3712; Kp=960;  break;
      case 3: src=s3; dst=d3; M=89;   K=1800; Mp=128;  Kp=1856; break;
      case 4: src=s4; dst=d4; M=1800; K=57;   Mp=1920; Kp=64;   break;
      default:src=s5; dst=d5; M=900;  K=1800; Mp=1024; Kp=1856; break;
    }
    int t = blockIdx.x * 256 + threadIdx.x;
    int K8 = Kp >> 3;
    if (t >= Mp * K8) return;
    int r = t / K8, c8 = (t - r * K8) * 8;
    unsigned pk[4];
#pragma unroll
    for (int q = 0; q < 4; ++q) {
        int ca = c8 + 2 * q, cb = ca + 1;
        float va = (r < M && ca < K) ? src[(size_t)r * K + ca] : 0.f;
        float vb = (r < M && cb < K) ? src[(size_t)r * K + cb] : 0.f;
        pk[q] = (unsigned)f2bf(va) | ((unsigned)f2bf(vb) << 16);
    }
    uint4 o; o.x = pk[0]; o.y = pk[1]; o.z = pk[2]; o.w = pk[3];
    *(uint4*)(dst + (size_t)r * Kp + c8) = o;
}

// ---------------- bf16 MFMA GEMM: dbuf + prefetch + counted vmcnt + T1/T2 swizzles ----------------
// BN = N-tile width (128 or 96). z: dir = z/split, s = z%split.
// mode 0: raw f32 -> C (+s*cstride)
// mode 1: raw bf16 -> Xo (+s*xstride)
// mode 5: softplus(acc+bias) -> bf16 -> Xo
// mode 6: in-proj fused: col<1800 -> bf16 Xo; col>=1800 -> silu -> bf16 G (=C0 cast, ld=1800)
template<int BN>
__global__ __launch_bounds__(256)
void gemm_mfma_k(const ushortT* __restrict__ A0, const ushortT* __restrict__ A1, int lda,
                 const ushortT* __restrict__ Bw, int ldb, int nkTotal, int split,
                 float* __restrict__ C0, float* __restrict__ C1, int ldc, size_t cstride,
                 ushortT* __restrict__ X0, ushortT* __restrict__ X1, int ldx, size_t xstride,
                 int M, int N, const float* __restrict__ bias, int mode)
{
    constexpr int JN = BN / 32;          // j-fragments per wave (4 or 3)
    __shared__ ushortT As[2][128 * 64];
    __shared__ ushortT Bs[2][BN * 64];

    // T1: bijective XCD-aware remap (m204) of the flattened block id.
    int gx = gridDim.x, gy = gridDim.y;
    int nwg = gx * gy * gridDim.z;
    int orig = (blockIdx.z * gy + blockIdx.y) * gx + blockIdx.x;
    int q8 = nwg >> 3, r8 = nwg & 7;
    int xcd = orig & 7, i8 = orig >> 3;
    int wg = (xcd < r8 ? xcd * (q8 + 1) : r8 * (q8 + 1) + (xcd - r8) * q8) + i8;
    int bx = wg % gx; int tmp = wg / gx; int by = tmp % gy; int bz = tmp / gy;

    int dir = bz / split, s = bz % split;
    int per = (nkTotal + split - 1) / split;
    int kt0 = s * per;
    int kcnt = nkTotal - kt0; if (kcnt > per) kcnt = per;
    int ktEnd = kt0 + kcnt;

    const ushortT* A = dir ? A1 : A0;
    float* C = (dir ? C1 : C0);
    ushortT* Xo = (dir ? X1 : X0);
    if (C && mode != 6)  C  += (size_t)s * cstride;
    if (Xo) Xo += (size_t)s * xstride;

    int tid = threadIdx.x;
    int lane = tid & 63, wave = tid >> 6;
    int wr = wave >> 1, wc = wave & 1;
    int m0 = by * 128, n0 = bx * BN;

    // T2: pre-swizzled global source column; LDS stays linear (rule #21).
    int csw = ((((tid >> 3) & 7) ^ (tid & 7)) << 3);
    auto stage = [&](int sb, int kt) {
#pragma unroll
        for (int r = 0; r < 4; ++r) {
            int idx = r * 256 + tid;
            int row = idx >> 3;
            gload_lds16(A + (size_t)(m0 + row) * lda + kt * 64 + csw, &As[sb][idx * 8]);
        }
#pragma unroll
        for (int r = 0; r < JN; ++r) {
            int idx = r * 256 + tid;
            int row = idx >> 3;
            gload_lds16(Bw + (size_t)(n0 + row) * ldb + kt * 64 + csw, &Bs[sb][idx * 8]);
        }
    };

    f32x4 acc[4][JN] = {};
    int rmask = (lane & 7) << 3;

    stage(0, kt0);
    for (int t = kt0; t < ktEnd; ++t) {
        int cur = (t - kt0) & 1;
        if (t + 1 < ktEnd) {
            stage(cur ^ 1, t + 1);
            if constexpr (BN == 128) asm volatile("s_waitcnt vmcnt(8)" ::: "memory");
            else                     asm volatile("s_waitcnt vmcnt(7)" ::: "memory");
        } else {
            asm volatile("s_waitcnt vmcnt(0)" ::: "memory");
        }
        __builtin_amdgcn_s_barrier();
        __builtin_amdgcn_sched_barrier(0);
#pragma unroll
        for (int ks = 0; ks < 2; ++ks) {
            short8 av[4], bv[JN];
            int kcol = (ks * 32 + (lane >> 4) * 8) ^ rmask;
#pragma unroll
            for (int i = 0; i < 4; ++i)
                av[i] = *(const short8*)(&As[cur][(wr * 64 + i * 16 + (lane & 15)) * 64 + kcol]);
#pragma unroll
            for (int j = 0; j < JN; ++j)
                bv[j] = *(const short8*)(&Bs[cur][(wc * (BN/2) + j * 16 + (lane & 15)) * 64 + kcol]);
#pragma unroll
            for (int i = 0; i < 4; ++i)
#pragma unroll
                for (int j = 0; j < JN; ++j)
                    acc[i][j] = __builtin_amdgcn_mfma_f32_16x16x32_bf16(bv[j], av[i], acc[i][j], 0, 0, 0);
        }
        __builtin_amdgcn_sched_barrier(0);
        __builtin_amdgcn_s_barrier();
        __builtin_amdgcn_sched_barrier(0);
    }

#pragma unroll
    for (int i = 0; i < 4; ++i) {
        int m = m0 + wr * 64 + i * 16 + (lane & 15);
        if (m >= M) continue;
#pragma unroll
        for (int j = 0; j < JN; ++j) {
            int nb = n0 + wc * (BN/2) + j * 16 + (lane >> 4) * 4;
            if (nb >= N) continue;     // N and nb are multiples of 4
            f32x4 v = acc[i][j];
            if (mode == 5) {
#pragma unroll
                for (int e = 0; e < 4; ++e)
                    v[e] = softplus_f(v[e] + bias[nb + e]);
            }
            if (mode == 6) {
                if (nb < D_INNER) {
                    unsigned lo, hi;
                    asm("v_cvt_pk_bf16_f32 %0, %1, %2" : "=v"(lo) : "v"(v[0]), "v"(v[1]));
                    asm("v_cvt_pk_bf16_f32 %0, %1, %2" : "=v"(hi) : "v"(v[2]), "v"(v[3]));
                    uint2 pk; pk.x = lo; pk.y = hi;
                    *(uint2*)(Xo + (size_t)m * ldx + nb) = pk;
                } else {
                    ushortT* G = (ushortT*)C;
#pragma unroll
                    for (int e = 0; e < 4; ++e) v[e] = silu_f(v[e]);
                    unsigned lo, hi;
                    asm("v_cvt_pk_bf16_f32 %0, %1, %2" : "=v"(lo) : "v"(v[0]), "v"(v[1]));
                    asm("v_cvt_pk_bf16_f32 %0, %1, %2" : "=v"(hi) : "v"(v[2]), "v"(v[3]));
                    uint2 pk; pk.x = lo; pk.y = hi;
                    *(uint2*)(G + (size_t)m * D_INNER + (nb - D_INNER)) = pk;
                }
            } else if (mode == 1 || mode == 5) {
                unsigned lo, hi;
                asm("v_cvt_pk_bf16_f32 %0, %1, %2" : "=v"(lo) : "v"(v[0]), "v"(v[1]));
                asm("v_cvt_pk_bf16_f32 %0, %1, %2" : "=v"(hi) : "v"(v[2]), "v"(v[3]));
                uint2 pk; pk.x = lo; pk.y = hi;
                *(uint2*)(Xo + (size_t)m * ldx + nb) = pk;
            } else {
                *(f32x4*)(C + (size_t)m * ldc + nb) = v;
            }
        }
    }
}

// ---------------- emb epilogue + rmsnorm (sums 4 bf16 partials) ----------------
__global__ __launch_bounds__(256)
void rmsnorm_emb_k(const ushortT* __restrict__ P, size_t pstride,
                   const float* __restrict__ b_emb, const float* __restrict__ pe,
                   const float* __restrict__ norm_w,
                   float* __restrict__ XS, ushortT* __restrict__ XN, int ldxn)
{
    int row = blockIdx.x;
    int l = (row >= SEQ_L) ? row - SEQ_L : row;
    float vv[4];
    float ssum = 0.f;
#pragma unroll
    for (int k = 0; k < 4; ++k) {
        int c = threadIdx.x + k * 256;
        if (c < 900) {
            size_t i = (size_t)row * 900 + c;
            float a = bf2f(P[i]) + bf2f(P[i + pstride]) + bf2f(P[i + 2 * pstride]) + bf2f(P[i + 3 * pstride]);
            float v = 30.f * (a + b_emb[c]) + pe[(size_t)l * 900 + c];
            vv[k] = v;
            ssum += v * v;
        } else vv[k] = 0.f;
    }
#pragma unroll
    for (int off = 32; off; off >>= 1) ssum += __shfl_down(ssum, off, 64);
    __shared__ float red[4];
    int wv = threadIdx.x >> 6;
    if ((threadIdx.x & 63) == 0) red[wv] = ssum;
    __syncthreads();
    float tot = red[0] + red[1] + red[2] + red[3];
    float scale = rsqrtf(tot / 900.f + 1e-5f);
#pragma unroll
    for (int k = 0; k < 4; ++k) {
        int c = threadIdx.x + k * 256;
        if (c < 900) {
            XS[(size_t)row * 900 + c] = vv[k];
            XN[(size_t)row * ldxn + c] = f2bf(vv[k] * scale * norm_w[c]);
        }
    }
}

// ---------------- final: 4 bf16 partials + residual -> rmsnorm -> out ----------------
__global__ __launch_bounds__(256)
void rmsnorm_final_k(const ushortT* __restrict__ ZP, size_t zstride,
                     const float* __restrict__ XS, const float* __restrict__ w,
                     float* __restrict__ out)
{
    int row = blockIdx.x;
    float vv[4];
    float ssum = 0.f;
#pragma unroll
    for (int k = 0; k < 4; ++k) {
        int c = threadIdx.x + k * 256;
        if (c < 900) {
            size_t i = (size_t)row * 900 + c;
            float v = bf2f(ZP[i]) + bf2f(ZP[i + zstride]) + bf2f(ZP[i + 2 * zstride]) + bf2f(ZP[i + 3 * zstride]) + XS[i];
            vv[k] = v;
            ssum += v * v;
        } else vv[k] = 0.f;
    }
#pragma unroll
    for (int off = 32; off; off >>= 1) ssum += __shfl_down(ssum, off, 64);
    __shared__ float red[4];
    int wv = threadIdx.x >> 6;
    if ((threadIdx.x & 63) == 0) red[wv] = ssum;
    __syncthreads();
    float tot = red[0] + red[1] + red[2] + red[3];
    float scale = rsqrtf(tot / 900.f + 1e-5f);
#pragma unroll
    for (int k = 0; k < 4; ++k) {
        int c = threadIdx.x + k * 256;
        if (c < 900) out[(size_t)row * 900 + c] = vv[k] * scale * w[c];
    }
}

// ---------------- conv: 4 channels/thread, single XR (xm half only), uint2 loads ----------------
__global__ __launch_bounds__(256)
void conv_silu_k(const ushortT* __restrict__ xr,   // [1800][1800] bf16 (xm half)
                 const float* __restrict__ w, const float* __restrict__ cb,
                 ushortT* __restrict__ xmc, ushortT* __restrict__ xbc)
{
    int t = blockIdx.x * 256 + threadIdx.x;
    if (t >= MROWS * (D_INNER / 4)) return;
    int d0 = (t % (D_INNER / 4)) * 4;
    int row = t / (D_INNER / 4);
    int l = row % SEQ_L;
    float wv[4][4], sf[4], sb[4];
#pragma unroll
    for (int ch = 0; ch < 4; ++ch) {
        f32x4 wl = *(const f32x4*)(w + (d0 + ch) * 4);
        wv[ch][0] = wl[0]; wv[ch][1] = wl[1]; wv[ch][2] = wl[2]; wv[ch][3] = wl[3];
        float b = cb[d0 + ch];
        sf[ch] = b; sb[ch] = b;
    }
    int rdp = 1796 - d0;
#pragma unroll
    for (int k = 0; k < 4; ++k) {
        int ll = l - 3 + k;
        if (ll < 0) continue;
        const ushortT* rp = xr + (size_t)(row - l + ll) * D_INNER;
        uint2 f = *(const uint2*)(rp + d0);
        float a0 = bf2f((ushortT)f.x), a1 = bf2f((ushortT)(f.x >> 16));
        float a2 = bf2f((ushortT)f.y), a3 = bf2f((ushortT)(f.y >> 16));
        sf[0] = fmaf(wv[0][k], a0, sf[0]);
        sf[1] = fmaf(wv[1][k], a1, sf[1]);
        sf[2] = fmaf(wv[2][k], a2, sf[2]);
        sf[3] = fmaf(wv[3][k], a3, sf[3]);
        uint2 rv = *(const uint2*)(rp + rdp);
        float b0 = bf2f((ushortT)rv.x), b1 = bf2f((ushortT)(rv.x >> 16));
        float b2 = bf2f((ushortT)rv.y), b3 = bf2f((ushortT)(rv.y >> 16));
        sb[0] = fmaf(wv[0][k], b3, sb[0]);
        sb[1] = fmaf(wv[1][k], b2, sb[1]);
        sb[2] = fmaf(wv[2][k], b1, sb[2]);
        sb[3] = fmaf(wv[3][k], b0, sb[3]);
    }
    uint2 om, ob;
    om.x = (unsigned)f2bf(silu_f(sf[0])) | ((unsigned)f2bf(silu_f(sf[1])) << 16);
    om.y = (unsigned)f2bf(silu_f(sf[2])) | ((unsigned)f2bf(silu_f(sf[3])) << 16);
    ob.x = (unsigned)f2bf(silu_f(sb[0])) | ((unsigned)f2bf(silu_f(sb[1])) << 16);
    ob.y = (unsigned)f2bf(silu_f(sb[2])) | ((unsigned)f2bf(silu_f(sb[3])) << 16);
    *(uint2*)(xmc + (size_t)row * KP_DI + d0) = om;
    *(uint2*)(xbc + (size_t)row * KP_DI + d0) = ob;
}

// ---------------- xp reduce: 8 f32 partials -> compact BC f32 + bf16 dt-input ----------------
__global__ __launch_bounds__(256)
void xp_reduce_k(const float* __restrict__ XPp, size_t pstride,
                 float* __restrict__ XDC, ushortT* __restrict__ XDMb, ushortT* __restrict__ XDBb)
{
    int t = blockIdx.x * 256 + threadIdx.x;
    if (t >= 2 * MROWS * 96) return;
    int dir = t / (MROWS * 96);
    int rem = t - dir * (MROWS * 96);
    int row = rem / 96, c = rem - row * 96;
    const float* basep = XPp + (size_t)dir * 8 * pstride + (size_t)row * 96 + c;
    float s = 0.f;
#pragma unroll
    for (int p = 0; p < 8; ++p) s += basep[p * pstride];
    ushortT* xdb = dir ? XDBb : XDMb;
    if (c < DT_RANK)           xdb[(size_t)row * KP_DT + c] = f2bf(s);
    else if (c < KP_DT)        xdb[(size_t)row * KP_DT + c] = 0;
    if (c >= DT_RANK && c < DT_RANK + 2 * D_STATE)
        XDC[((size_t)dir * MROWS + row) * 32 + (c - DT_RANK)] = s;
}

// ---------------- scan level 1 (delta bf16 in, HL bf16 out) ----------------
__global__ __launch_bounds__(256)
void scan_l1_k(const ushortT* __restrict__ DMb, const ushortT* __restrict__ DBb,
               const ushortT* __restrict__ Um, const ushortT* __restrict__ Ub,
               const float* __restrict__ XDC, const float* __restrict__ A_log,
               ushortT* __restrict__ HL, float* __restrict__ SD)
{
    int d = blockIdx.x * 256 + threadIdx.x;
    if (d >= D_INNER) return;
    int c = blockIdx.y, zz = blockIdx.z;
    int b = zz >> 1, dir = zz & 1;
    const ushortT* DL = dir ? DBb : DMb;
    const ushortT* U = dir ? Ub : Um;
    const float* XD = XDC + (size_t)dir * MROWS * 32;
    float Aa[D_STATE];
#pragma unroll
    for (int n = 0; n < D_STATE; ++n) Aa[n] = -__expf(A_log[d * D_STATE + n]);
    float h[D_STATE] = {};
    float S = 0.f;
    int l0 = c * CLEN;
    for (int i = 0; i < CLEN; ++i) {
        size_t rowi = (size_t)b * SEQ_L + l0 + i;
        float delta = bf2f(DL[rowi * D_INNER + d]);
        float u = bf2f(U[rowi * KP_DI + d]);
        const float* bc = XD + rowi * 32;
        float du = delta * u;
        S += delta;
#pragma unroll
        for (int n = 0; n < D_STATE; ++n)
            h[n] = fmaf(__expf(delta * Aa[n]), h[n], du * bc[n]);
    }
    ushortT* hp = HL + ((size_t)(zz * NCHUNK + c) * D_INNER + d) * D_STATE;
    unsigned pk[8];
#pragma unroll
    for (int q = 0; q < 8; ++q)
        asm("v_cvt_pk_bf16_f32 %0, %1, %2" : "=v"(pk[q]) : "v"(h[2*q]), "v"(h[2*q+1]));
    uint4 lo4; lo4.x = pk[0]; lo4.y = pk[1]; lo4.z = pk[2]; lo4.w = pk[3];
    uint4 hi4; hi4.x = pk[4]; hi4.y = pk[5]; hi4.z = pk[6]; hi4.w = pk[7];
    *(uint4*)(hp) = lo4;
    *(uint4*)(hp + 8) = hi4;
    SD[(size_t)(zz * NCHUNK + c) * D_INNER + d] = S;
}

// ---------------- scan level 2: 4 states/thread, uint2 HL access ----------------
__global__ __launch_bounds__(256)
void scan_l2_k(ushortT* __restrict__ HL, const float* __restrict__ SD,
               const float* __restrict__ A_log)
{
    int t = blockIdx.x * 256 + threadIdx.x;
    if (t >= 4 * D_INNER * 4) return;
    int nq = t & 3;
    int d = (t >> 2) % D_INNER;
    int zz = t / (D_INNER * 4);
    float Aa[4];
#pragma unroll
    for (int q = 0; q < 4; ++q) Aa[q] = -__expf(A_log[d * D_STATE + nq * 4 + q]);
    float h0[4] = {};
    for (int c = 0; c < NCHUNK; ++c) {
        size_t base = ((size_t)(zz * NCHUNK + c) * D_INNER + d) * D_STATE + nq * 4;
        uint2 pkv = *(uint2*)(HL + base);
        float hl[4] = { bf2f((ushortT)pkv.x), bf2f((ushortT)(pkv.x >> 16)),
                        bf2f((ushortT)pkv.y), bf2f((ushortT)(pkv.y >> 16)) };
        float Sd = SD[(size_t)(zz * NCHUNK + c) * D_INNER + d];
        uint2 o;
        o.x = (unsigned)f2bf(h0[0]) | ((unsigned)f2bf(h0[1]) << 16);
        o.y = (unsigned)f2bf(h0[2]) | ((unsigned)f2bf(h0[3]) << 16);
        *(uint2*)(HL + base) = o;
#pragma unroll
        for (int q = 0; q < 4; ++q)
            h0[q] = fmaf(__expf(Aa[q] * Sd), h0[q], hl[q]);
    }
}

// ---------------- scan level 3 + gate fused: both dirs per thread, writes YC bf16 ----------------
__global__ __launch_bounds__(256)
void scan3_gate_k(const ushortT* __restrict__ DMb, const ushortT* __restrict__ DBb,
                  const ushortT* __restrict__ Um, const ushortT* __restrict__ Ub,
                  const float* __restrict__ XDC, const float* __restrict__ A_log,
                  const float* __restrict__ Dv, const ushortT* __restrict__ HL,
                  const ushortT* __restrict__ G, ushortT* __restrict__ YC)
{
    int d = blockIdx.x * 256 + threadIdx.x;
    if (d >= D_INNER) return;
    int c = blockIdx.y, b = blockIdx.z;
    int rd = D_INNER - 1 - d;
    float Aa0[D_STATE], Aa1[D_STATE], h0[D_STATE], h1[D_STATE];
#pragma unroll
    for (int n = 0; n < D_STATE; ++n) Aa0[n] = -__expf(A_log[d * D_STATE + n]);
#pragma unroll
    for (int n = 0; n < D_STATE; ++n) Aa1[n] = -__expf(A_log[rd * D_STATE + n]);
    const ushortT* hp0 = HL + ((size_t)((b * 2) * NCHUNK + c) * D_INNER + d) * D_STATE;
    const ushortT* hp1 = HL + ((size_t)((b * 2 + 1) * NCHUNK + c) * D_INNER + rd) * D_STATE;
    {
        uint4 a0 = *(const uint4*)(hp0);
        uint4 a1 = *(const uint4*)(hp0 + 8);
        unsigned ww[8] = {a0.x, a0.y, a0.z, a0.w, a1.x, a1.y, a1.z, a1.w};
#pragma unroll
        for (int q = 0; q < 8; ++q) {
            h0[2*q]   = bf2f((ushortT)ww[q]);
            h0[2*q+1] = bf2f((ushortT)(ww[q] >> 16));
        }
        uint4 b0 = *(const uint4*)(hp1);
        uint4 b1 = *(const uint4*)(hp1 + 8);
        unsigned vv[8] = {b0.x, b0.y, b0.z, b0.w, b1.x, b1.y, b1.z, b1.w};
#pragma unroll
        for (int q = 0; q < 8; ++q) {
            h1[2*q]   = bf2f((ushortT)vv[q]);
            h1[2*q+1] = bf2f((ushortT)(vv[q] >> 16));
        }
    }
    float Dd0 = Dv[d], Dd1 = Dv[rd];
    const float* XD0 = XDC;
    const float* XD1 = XDC + (size_t)MROWS * 32;
    int l0 = c * CLEN;
    for (int i = 0; i < CLEN; ++i) {
        size_t rowi = (size_t)b * SEQ_L + l0 + i;
        float delta0 = bf2f(DMb[rowi * D_INNER + d]);
        float u0 = bf2f(Um[rowi * KP_DI + d]);
        const float* bc0 = XD0 + rowi * 32;
        float du0 = delta0 * u0;
        float acc0 = u0 * Dd0;
#pragma unroll
        for (int n = 0; n < D_STATE; ++n) {
            h0[n] = fmaf(__expf(delta0 * Aa0[n]), h0[n], du0 * bc0[n]);
            acc0 = fmaf(h0[n], bc0[D_STATE + n], acc0);
        }
        float delta1 = bf2f(DBb[rowi * D_INNER + rd]);
        float u1 = bf2f(Ub[rowi * KP_DI + rd]);
        const float* bc1 = XD1 + rowi * 32;
        float du1 = delta1 * u1;
        float acc1 = u1 * Dd1;
#pragma unroll
        for (int n = 0; n < D_STATE; ++n) {
            h1[n] = fmaf(__expf(delta1 * Aa1[n]), h1[n], du1 * bc1[n]);
            acc1 = fmaf(h1[n], bc1[D_STATE + n], acc1);
        }
        float g = bf2f(G[rowi * D_INNER + d]);
        YC[rowi * KP_DI + d] = f2bf((acc0 + acc1) * g);
    }
}

extern "C" void kernel_launch(void* const* d_in, const int* in_sizes, int n_in,
                              void* d_out, int out_size, void* d_ws, size_t ws_size,
                              hipStream_t stream)
{
    const float* inp    = (const float*)d_in[0];
    const float* W_emb  = (const float*)d_in[1];
    const float* b_emb  = (const float*)d_in[2];
    const float* norm_w = (const float*)d_in[3];
    const float* W_in   = (const float*)d_in[4];
    const float* conv_w = (const float*)d_in[5];
    const float* conv_b = (const float*)d_in[6];
    const float* W_xp   = (const float*)d_in[7];
    const float* W_dt   = (const float*)d_in[8];
    const float* b_dt   = (const float*)d_in[9];
    const float* A_log  = (const float*)d_in[10];
    const float* Dv     = (const float*)d_in[11];
    const float* W_out  = (const float*)d_in[12];
    const float* normf_w= (const float*)d_in[13];
    const float* pe     = (const float*)d_in[14];

    char* base = (char*)d_ws;
    size_t off = 0;
    auto alloc = [&](size_t bytes) { char* p = base + off; off += (bytes + 255) & ~(size_t)255; return p; };

    float*   XS      = (float*)alloc(6480000);        // residual f32, lives to end
    // arena1: XPp (11.06MB, xp partials) -> HL bf16 (10.37MB)+SD(1.296MB)
    char*    arena1  = alloc(22032000);
    float*   XPp     = (float*)arena1;
    ushortT* HL      = (ushortT*)arena1;              // 4 x 45 x 1800 x 16 bf16 = 10.368 MB
    float*   SD      = (float*)(arena1 + 10368000);   // 4 x 45 x 1800 f32 = 1.296 MB
    ushortT* inp_bf  = (ushortT*)alloc(3686400);      // 1920x960; later start of YC
    ushortT* XN_bf   = (ushortT*)alloc(3686400);      // contiguous after inp_bf (YC spillover)
    ushortT* Wemb_bf = (ushortT*)alloc(1966080);      // 1024x960; after emb: XDC+XDM_bf+XDB_bf
    ushortT* Win_bf  = (ushortT*)alloc(7127040);      // 3712x960; after in-proj: XMC_bf (1920x1856)
    ushortT* Wxp_bf  = (ushortT*)alloc(475136);       // 128x1856
    ushortT* Wdt_bf  = (ushortT*)alloc(245760);       // 1920x64
    ushortT* Wout_bf = (ushortT*)alloc(3801088);      // 1024x1856
    ushortT* XBC_bf  = (ushortT*)alloc(7127040);      // 1920x1856
    // arena2 (25.92MB): Pemb(bf16 x4) -> XR (1800x1800 bf16) -> DMb/DBb(bf16) -> ZP(bf16 x4)
    char*    arena2  = alloc(25920000);
    ushortT* Pemb    = (ushortT*)arena2;
    ushortT* XR      = (ushortT*)arena2;              // 1800x1800 bf16 (xm half only)
    ushortT* DMb     = (ushortT*)arena2;
    ushortT* DBb     = DMb + (size_t)MROWS * D_INNER;
    ushortT* ZP      = (ushortT*)arena2;
    ushortT* G_bf    = (ushortT*)alloc(6480000);      // 1800x1800 bf16 (written by in-proj GEMM)

    // aliases into dead regions
    float*   XDC     = (float*)Wemb_bf;               // 2x1800x32 f32 = 460800 B
    ushortT* XDM_bf  = (ushortT*)((char*)Wemb_bf + 460800);   // 1920x64 bf16
    ushortT* XDB_bf  = (ushortT*)((char*)Wemb_bf + 706560);
    ushortT* XMC_bf  = Win_bf;                        // 1920x1856 bf16, exact fit
    ushortT* YC_bf   = inp_bf;                        // 1920x1856 spans inp_bf+XN_bf (7.13<=7.37MB)

    dim3 blk(256);
    auto cdiv = [](int a, int b) { return (a + b - 1) / b; };
    const size_t PSTR  = 1620000;   // 1800*900 elements (bf16 partial stride)
    const size_t XPSTR = 172800;    // 1800*96 f32 partial stride

    // 0) all conversions (8 cols/thread)
    hipLaunchKernelGGL(cvt_all_k, dim3(1740, 6), blk, 0, stream,
                       inp, inp_bf, W_emb, Wemb_bf, W_in, Win_bf,
                       W_xp, Wxp_bf, W_dt, Wdt_bf, W_out, Wout_bf);
    // 1) embedding GEMM split-4 -> Pemb (bf16 partials)
    hipLaunchKernelGGL((gemm_mfma_k<128>), dim3(8, 15, 4), blk, 0, stream,
                       inp_bf, inp_bf, KP_DM, Wemb_bf, KP_DM, KP_DM/64, 4,
                       (float*)nullptr, (float*)nullptr, 0, (size_t)0,
                       Pemb, Pemb, 900, PSTR,
                       MROWS, 900, (const float*)nullptr, 1);
    // 2) emb epilogue + rmsnorm -> XS, XN_bf
    hipLaunchKernelGGL(rmsnorm_emb_k, dim3(MROWS), blk, 0, stream,
                       Pemb, PSTR, b_emb, pe, norm_w, XS, XN_bf, KP_DM);
    // 3) in-proj split-1, fused G epilogue -> XR (xm half bf16) + G_bf
    hipLaunchKernelGGL((gemm_mfma_k<128>), dim3(29, 15, 1), blk, 0, stream,
                       XN_bf, XN_bf, KP_DM, Win_bf, KP_DM, KP_DM/64, 1,
                       (float*)G_bf, (float*)G_bf, 0, (size_t)0,
                       XR, XR, D_INNER, (size_t)0,
                       MROWS, 3600, (const float*)nullptr, 6);
    // 4) conv + silu (4 ch/thread, single XR)
    hipLaunchKernelGGL(conv_silu_k, dim3(cdiv(MROWS * (D_INNER/4), 256)), blk, 0, stream,
                       XR, conv_w, conv_b, XMC_bf, XBC_bf);
    // 5) x-proj split-8 both dirs, 96-wide tile -> XPp (f32 partials)
    hipLaunchKernelGGL((gemm_mfma_k<96>), dim3(1, 15, 16), blk, 0, stream,
                       XMC_bf, XBC_bf, KP_DI, Wxp_bf, KP_DI, KP_DI/64, 8,
                       XPp, XPp + 8 * XPSTR, 96, XPSTR,
                       (ushortT*)nullptr, (ushortT*)nullptr, 0, (size_t)0,
                       MROWS, 96, (const float*)nullptr, 0);
    // 5b) xp reduce -> XDC (compact BC) + bf16 dt inputs
    hipLaunchKernelGGL(xp_reduce_k, dim3(cdiv(2 * MROWS * 96, 256)), blk, 0, stream,
                       XPp, XPSTR, XDC, XDM_bf, XDB_bf);
    // 6) dt GEMM both dirs + fast-softplus -> DMb, DBb (bf16)
    hipLaunchKernelGGL((gemm_mfma_k<128>), dim3(15, 15, 2), blk, 0, stream,
                       XDM_bf, XDB_bf, KP_DT, Wdt_bf, KP_DT, 1, 1,
                       (float*)nullptr, (float*)nullptr, 0, (size_t)0,
                       DMb, DBb, D_INNER, (size_t)0,
                       MROWS, D_INNER, b_dt, 5);
    // 7) chunked scan (HL bf16)
    hipLaunchKernelGGL(scan_l1_k, dim3(cdiv(D_INNER, 256), NCHUNK, 4), blk, 0, stream,
                       DMb, DBb, XMC_bf, XBC_bf, XDC, A_log, HL, SD);
    hipLaunchKernelGGL(scan_l2_k, dim3(cdiv(4 * D_INNER * 4, 256)), blk, 0, stream, HL, SD, A_log);
    // 7c) level 3 + gate fused -> YC bf16
    hipLaunchKernelGGL(scan3_gate_k, dim3(cdiv(D_INNER, 256), NCHUNK, 2), blk, 0, stream,
                       DMb, DBb, XMC_bf, XBC_bf, XDC, A_log, Dv, HL, G_bf, YC_bf);
    // 9) out-proj split-4 -> ZP (bf16 partials)
    hipLaunchKernelGGL((gemm_mfma_k<128>), dim3(8, 15, 4), blk, 0, stream,
                       YC_bf, YC_bf, KP_DI, Wout_bf, KP_DI, KP_DI/64, 4,
                       (float*)nullptr, (float*)nullptr, 0, (size_t)0,
                       ZP, ZP, 900, PSTR,
                       MROWS, 900, (const float*)nullptr, 1);
    // 10) final reduce + residual + rmsnorm -> d_out
    hipLaunchKernelGGL(rmsnorm_final_k, dim3(MROWS), blk, 0, stream,
                       ZP, PSTR, XS, normf_w, (float*)d_out);
}